// Round 19
// baseline (94.494 us; speedup 1.0000x reference)
//
#include <hip/hip_runtime.h>

#define D 32
#define CSH 6                      // 64 nodes per coarse bucket
#define KMASK 63
#define PSH 23                     // payload bits (node id) -> N must be <= 2^23
#define PMASK ((1u << PSH) - 1u)
#define NBMAX 1024

typedef unsigned int uint;

// f32 -> bf16 round-to-nearest-even, and pack/unpack helpers
__device__ inline uint bf16rne(float f) {
    uint u = __float_as_uint(f);
    return (u + 0x7FFFu + ((u >> 16) & 1u)) >> 16;
}
__device__ inline float bf_lo(uint w) { return __uint_as_float(w << 16); }
__device__ inline float bf_hi(uint w) { return __uint_as_float(w & 0xFFFF0000u); }
__device__ inline uint bf_pack(float x, float y) { return bf16rne(x) | (bf16rne(y) << 16); }

// ---- zero the bucket cursors ----
__global__ void zero_kernel(int* __restrict__ p, int n) {
    int i = blockIdx.x * 1024 + threadIdx.x;
    if (i < n) p[i] = 0;
}

// ---- merged coarse scatter with LDS staging; 1024-bucket wave-shfl scan ----
__global__ void __launch_bounds__(1024)
coarse_scatter(const int* __restrict__ src, const int* __restrict__ dst,
               int* __restrict__ gCurD, int* __restrict__ gCurS,
               uint* __restrict__ coarseD, uint* __restrict__ coarseS,
               int E, int cap) {
    __shared__ uint stageD[4096], stageS[4096];          // 32 KB
    __shared__ int hD[NBMAX], hS[NBMAX];
    __shared__ int offD[NBMAX + 1], offS[NBMAX + 1];
    __shared__ int baseD[NBMAX], baseS[NBMAX];
    __shared__ int partD[16], partS[16];
    int t = threadIdx.x;
    hD[t] = 0; hS[t] = 0;
    __syncthreads();
    int s[4], d[4], lpD[4], lpS[4];
    int j0 = blockIdx.x * 4096 + 4 * t;     // this thread's 4 consecutive edges
    int nv = 0;
    if (j0 + 3 < E) {
        int4 s4 = *(const int4*)(src + j0);
        int4 d4 = *(const int4*)(dst + j0);
        s[0] = s4.x; s[1] = s4.y; s[2] = s4.z; s[3] = s4.w;
        d[0] = d4.x; d[1] = d4.y; d[2] = d4.z; d[3] = d4.w;
        nv = 4;
    } else {
        for (int u = 0; u < 4; ++u) {
            int j = j0 + u;
            if (j < E) { s[nv] = src[j]; d[nv] = dst[j]; ++nv; }
        }
    }
    for (int u = 0; u < nv; ++u) {
        lpD[u] = atomicAdd(&hD[d[u] >> CSH], 1);
        lpS[u] = atomicAdd(&hS[s[u] >> CSH], 1);
    }
    __syncthreads();
    // wave-shfl scan: thread t owns bucket t (both directions in registers)
    int w = t >> 6, l = t & 63;
    int vD = hD[t], vS = hS[t];
    int iD = vD, iS = vS;
    #pragma unroll
    for (int off = 1; off < 64; off <<= 1) {
        int xD = __shfl_up(iD, off, 64);
        int xS = __shfl_up(iS, off, 64);
        if (l >= off) { iD += xD; iS += xS; }
    }
    if (l == 63) { partD[w] = iD; partS[w] = iS; }
    __syncthreads();
    if (t < 32) {                        // lanes 0-15: D partials, 16-31: S partials
        int idx = t & 15;
        int v = (t < 16) ? partD[idx] : partS[idx];
        int incl = v;
        #pragma unroll
        for (int off = 1; off < 16; off <<= 1) {
            int x = __shfl_up(incl, off, 16);
            if (idx >= off) incl += x;
        }
        if (t < 16) partD[idx] = incl - v; else partS[idx] = incl - v;
    }
    __syncthreads();
    {
        int inclD = iD + partD[w];
        int inclS = iS + partS[w];
        offD[t] = inclD - vD;
        offS[t] = inclS - vS;
        if (vD) baseD[t] = atomicAdd(&gCurD[t], vD);
        if (vS) baseS[t] = atomicAdd(&gCurS[t], vS);
        if (t == NBMAX - 1) { offD[NBMAX] = inclD; offS[NBMAX] = inclS; }
    }
    __syncthreads();
    // scatter into LDS stage, ordered by bucket
    for (int u = 0; u < nv; ++u) {
        stageD[offD[d[u] >> CSH] + lpD[u]] = ((uint)(d[u] & KMASK) << PSH) | (uint)s[u];
        stageS[offS[s[u] >> CSH] + lpS[u]] = ((uint)(s[u] & KMASK) << PSH) | (uint)d[u];
    }
    __syncthreads();
    // coalesced copy-out: consecutive threads write consecutive run entries
    int totD = offD[NBMAX];
    for (int j = t; j < totD; j += 1024) {
        int lo = 0, hi = NBMAX;                  // largest b with offD[b] <= j
        while (hi - lo > 1) { int mid = (lo + hi) >> 1; if (offD[mid] <= j) lo = mid; else hi = mid; }
        int rel = baseD[lo] + (j - offD[lo]);
        if (rel < cap) coarseD[(size_t)lo * cap + rel] = stageD[j];
    }
    int totS = offS[NBMAX];
    for (int j = t; j < totS; j += 1024) {
        int lo = 0, hi = NBMAX;
        while (hi - lo > 1) { int mid = (lo + hi) >> 1; if (offS[mid] <= j) lo = mid; else hi = mid; }
        int rel = baseS[lo] + (j - offS[lo]);
        if (rel < cap) coarseS[(size_t)lo * cap + rel] = stageS[j];
    }
}

// ---- merged deg histogram + dense matmul (64-node buckets, 512 threads) ----
__global__ void __launch_bounds__(512)
matmul_deg_kernel(const float* __restrict__ X, const float* __restrict__ W,
                  const uint* __restrict__ coarseD, const int* __restrict__ gCurD,
                  uint* __restrict__ hs16, int N, int cap) {
    __shared__ float Wl[D * D];        // 4 KB
    __shared__ float Xl[64 * D];       // 8 KB
    __shared__ int cnt[64];
    int b = blockIdx.x, t = threadIdx.x;   // 512
    int nodeLo = b << CSH;
    if (t < 64) cnt[t] = 0;
    for (int k = t; k < D * D; k += 512) Wl[k] = W[k];
    for (int i = t; i < 64 * D; i += 512) {
        int node = nodeLo + (i >> 5);
        Xl[i] = (node < N) ? X[(size_t)node * D + (i & 31)] : 0.f;
    }
    __syncthreads();
    size_t lo = (size_t)b * cap;
    int n = min(gCurD[b], cap - 256);
    int n4 = n >> 2;
    const uint4* c4 = (const uint4*)(coarseD + lo);
    for (int kk = t; kk < n4; kk += 512) {
        uint4 e4 = c4[kk];
        atomicAdd(&cnt[e4.x >> PSH], 1);
        atomicAdd(&cnt[e4.y >> PSH], 1);
        atomicAdd(&cnt[e4.z >> PSH], 1);
        atomicAdd(&cnt[e4.w >> PSH], 1);
    }
    for (int kk = 4 * n4 + t; kk < n; kk += 512)
        atomicAdd(&cnt[coarseD[lo + kk] >> PSH], 1);
    __syncthreads();
    // 4 passes of 16 rows x 32 cols
    int c = t & 31;
    #pragma unroll
    for (int pass = 0; pass < 4; ++pass) {
        int r = pass * 16 + (t >> 5);
        int node = nodeLo + r;
        float acc = 0.f;
        #pragma unroll
        for (int k = 0; k < D; ++k) acc += Xl[r * D + k] * Wl[k * D + c];
        acc *= rsqrtf((float)(cnt[r] + 1));              // +1 self-loop
        float other = __shfl_xor(acc, 1);
        if (node < N && (c & 1) == 0)
            hs16[(size_t)node * 16 + (c >> 1)] = bf_pack(acc, other);
    }
}

// ---- fused D-direction sort + conv gather (64-node buckets, 512 threads) ----
__global__ void __launch_bounds__(512)
conv_fused(const uint* __restrict__ coarseD, const int* __restrict__ gCurD,
           const uint* __restrict__ hs16, const float* __restrict__ bias,
           uint* __restrict__ h2_16, int N, int cap) {
    extern __shared__ uint adjL[];               // cap entries (dynamic LDS)
    __shared__ int cnt[64];
    __shared__ int rs[64];
    __shared__ int degL[64];
    int b = blockIdx.x;
    int t = threadIdx.x;   // 512
    int nodeLo = b << CSH;
    int nNodes = min(64, N - nodeLo);
    if (t < 64) cnt[t] = 0;
    __syncthreads();
    size_t lo = (size_t)b * cap;
    int n = min(gCurD[b], cap - 256);
    int n4 = n >> 2;
    const uint4* c4 = (const uint4*)(coarseD + lo);
    for (int kk = t; kk < n4; kk += 512) {
        uint4 e4 = c4[kk];
        atomicAdd(&cnt[e4.x >> PSH], 1);
        atomicAdd(&cnt[e4.y >> PSH], 1);
        atomicAdd(&cnt[e4.z >> PSH], 1);
        atomicAdd(&cnt[e4.w >> PSH], 1);
    }
    for (int kk = 4 * n4 + t; kk < n; kk += 512)
        atomicAdd(&cnt[coarseD[lo + kk] >> PSH], 1);
    __syncthreads();
    if (t < 64) {                                // single-wave 64-entry scan
        int a = cnt[t];
        int pa = (a + 3) & ~3;
        int incl = pa;
        #pragma unroll
        for (int off = 1; off < 64; off <<= 1) {
            int x = __shfl_up(incl, off, 64);
            if (t >= off) incl += x;
        }
        int excl = incl - pa;
        rs[t] = excl;
        degL[t] = a;
        cnt[t] = excl;                           // cursor
    }
    __syncthreads();
    for (int kk = t; kk < n; kk += 512) {        // scatter (coarse is L2-hot)
        uint e = coarseD[lo + kk];
        int pos = atomicAdd(&cnt[e >> PSH], 1);
        if (pos < cap) adjL[pos] = e & PMASK;
    }
    __syncthreads();
    // gather phase: wave w handles nodes w, w+8, w+16, ...
    int wave = t >> 6, lane = t & 63;
    int p = lane & 15, slot = lane >> 4;
    for (int nl = wave; nl < nNodes; nl += 8) {
        int s = rs[nl];
        int e = s + degL[nl];
        float ax0 = 0.f, ay0 = 0.f, ax1 = 0.f, ay1 = 0.f;
        float ax2 = 0.f, ay2 = 0.f, ax3 = 0.f, ay3 = 0.f;
        int k = s;
        for (; k + 31 < e; k += 32) {            // 8 row-gathers in flight
            uint4 iv0 = *(const uint4*)(adjL + k + slot * 4);
            uint4 iv1 = *(const uint4*)(adjL + k + 16 + slot * 4);
            uint w0 = hs16[iv0.x * 16 + p];
            uint w1 = hs16[iv0.y * 16 + p];
            uint w2 = hs16[iv0.z * 16 + p];
            uint w3 = hs16[iv0.w * 16 + p];
            uint w4 = hs16[iv1.x * 16 + p];
            uint w5 = hs16[iv1.y * 16 + p];
            uint w6 = hs16[iv1.z * 16 + p];
            uint w7 = hs16[iv1.w * 16 + p];
            ax0 += bf_lo(w0); ay0 += bf_hi(w0);
            ax1 += bf_lo(w1); ay1 += bf_hi(w1);
            ax2 += bf_lo(w2); ay2 += bf_hi(w2);
            ax3 += bf_lo(w3); ay3 += bf_hi(w3);
            ax0 += bf_lo(w4); ay0 += bf_hi(w4);
            ax1 += bf_lo(w5); ay1 += bf_hi(w5);
            ax2 += bf_lo(w6); ay2 += bf_hi(w6);
            ax3 += bf_lo(w7); ay3 += bf_hi(w7);
        }
        for (; k + 15 < e; k += 16) {
            uint4 iv = *(const uint4*)(adjL + k + slot * 4);
            uint w0 = hs16[iv.x * 16 + p];
            uint w1 = hs16[iv.y * 16 + p];
            uint w2 = hs16[iv.z * 16 + p];
            uint w3 = hs16[iv.w * 16 + p];
            ax0 += bf_lo(w0); ay0 += bf_hi(w0);
            ax1 += bf_lo(w1); ay1 += bf_hi(w1);
            ax2 += bf_lo(w2); ay2 += bf_hi(w2);
            ax3 += bf_lo(w3); ay3 += bf_hi(w3);
        }
        for (; k < e; k += 4) {
            int kk = k + slot;
            if (kk < e) {
                uint w = hs16[adjL[kk] * 16 + p];
                ax0 += bf_lo(w); ay0 += bf_hi(w);
            }
        }
        float accx = (ax0 + ax1) + (ax2 + ax3);
        float accy = (ay0 + ay1) + (ay2 + ay3);
        accx += __shfl_xor(accx, 16); accy += __shfl_xor(accy, 16);
        accx += __shfl_xor(accx, 32); accy += __shfl_xor(accy, 32);
        if (slot == 0) {
            int node = nodeLo + nl;
            uint wself = hs16[(size_t)node * 16 + p];
            float di = rsqrtf((float)(degL[nl] + 1));
            float vx = di * (accx + bf_lo(wself)) + bias[2 * p];
            float vy = di * (accy + bf_hi(wself)) + bias[2 * p + 1];
            h2_16[(size_t)node * 16 + p] = bf_pack(fmaxf(vx, 0.f), fmaxf(vy, 0.f));
        }
    }
}

// ---- fused S-direction sort + pow gather (64-node buckets, 512 threads) ----
__global__ void __launch_bounds__(512)
pow_fused(const uint* __restrict__ coarseS, const int* __restrict__ gCurS,
          const uint* __restrict__ h2_16, float* __restrict__ out, int N, int cap) {
    extern __shared__ uint adjL[];               // cap entries (dynamic LDS)
    __shared__ int cnt[64];
    __shared__ int rs[64];
    __shared__ int degL[64];
    __shared__ uint self[64 * 16];               // 4 KB
    int b = blockIdx.x;
    int t = threadIdx.x;   // 512
    int nodeLo = b << CSH;
    int nNodes = min(64, N - nodeLo);
    if (t < 64) cnt[t] = 0;
    for (int i = t; i < nNodes * 16; i += 512)
        self[i] = h2_16[(size_t)(nodeLo + (i >> 4)) * 16 + (i & 15)];
    __syncthreads();
    size_t lo = (size_t)b * cap;
    int n = min(gCurS[b], cap - 256);
    int n4 = n >> 2;
    const uint4* c4 = (const uint4*)(coarseS + lo);
    for (int kk = t; kk < n4; kk += 512) {
        uint4 e4 = c4[kk];
        atomicAdd(&cnt[e4.x >> PSH], 1);
        atomicAdd(&cnt[e4.y >> PSH], 1);
        atomicAdd(&cnt[e4.z >> PSH], 1);
        atomicAdd(&cnt[e4.w >> PSH], 1);
    }
    for (int kk = 4 * n4 + t; kk < n; kk += 512)
        atomicAdd(&cnt[coarseS[lo + kk] >> PSH], 1);
    __syncthreads();
    if (t < 64) {                                // single-wave 64-entry scan
        int a = cnt[t];
        int pa = (a + 3) & ~3;
        int incl = pa;
        #pragma unroll
        for (int off = 1; off < 64; off <<= 1) {
            int x = __shfl_up(incl, off, 64);
            if (t >= off) incl += x;
        }
        int excl = incl - pa;
        rs[t] = excl;
        degL[t] = a;
        cnt[t] = excl;                           // cursor
    }
    __syncthreads();
    for (int kk = t; kk < n; kk += 512) {        // scatter (coarse is L2-hot)
        uint e = coarseS[lo + kk];
        int pos = atomicAdd(&cnt[e >> PSH], 1);
        if (pos < cap) adjL[pos] = e & PMASK;
    }
    __syncthreads();
    // gather phase: wave w handles nodes w, w+8, w+16, ...
    int wave = t >> 6, lane = t & 63;
    int p = lane & 15, slot = lane >> 4;
    for (int nl = wave; nl < nNodes; nl += 8) {
        int s = rs[nl];
        int e = s + degL[nl];
        uint wh = self[nl * 16 + p];
        float hx = bf_lo(wh), hy = bf_hi(wh);
        float ax0 = 0.f, ay0 = 0.f, ax1 = 0.f, ay1 = 0.f;
        float ax2 = 0.f, ay2 = 0.f, ax3 = 0.f, ay3 = 0.f;
        int k = s;
        for (; k + 31 < e; k += 32) {            // 8 row-gathers in flight
            uint4 iv0 = *(const uint4*)(adjL + k + slot * 4);
            uint4 iv1 = *(const uint4*)(adjL + k + 16 + slot * 4);
            uint w0 = h2_16[iv0.x * 16 + p];
            uint w1 = h2_16[iv0.y * 16 + p];
            uint w2 = h2_16[iv0.z * 16 + p];
            uint w3 = h2_16[iv0.w * 16 + p];
            uint w4 = h2_16[iv1.x * 16 + p];
            uint w5 = h2_16[iv1.y * 16 + p];
            uint w6 = h2_16[iv1.z * 16 + p];
            uint w7 = h2_16[iv1.w * 16 + p];
            float vx0 = hx - bf_lo(w0), vy0 = hy - bf_hi(w0);
            float vx1 = hx - bf_lo(w1), vy1 = hy - bf_hi(w1);
            float vx2 = hx - bf_lo(w2), vy2 = hy - bf_hi(w2);
            float vx3 = hx - bf_lo(w3), vy3 = hy - bf_hi(w3);
            ax0 += vx0 * vx0; ay0 += vy0 * vy0;
            ax1 += vx1 * vx1; ay1 += vy1 * vy1;
            ax2 += vx2 * vx2; ay2 += vy2 * vy2;
            ax3 += vx3 * vx3; ay3 += vy3 * vy3;
            float vx4 = hx - bf_lo(w4), vy4 = hy - bf_hi(w4);
            float vx5 = hx - bf_lo(w5), vy5 = hy - bf_hi(w5);
            float vx6 = hx - bf_lo(w6), vy6 = hy - bf_hi(w6);
            float vx7 = hx - bf_lo(w7), vy7 = hy - bf_hi(w7);
            ax0 += vx4 * vx4; ay0 += vy4 * vy4;
            ax1 += vx5 * vx5; ay1 += vy5 * vy5;
            ax2 += vx6 * vx6; ay2 += vy6 * vy6;
            ax3 += vx7 * vx7; ay3 += vy7 * vy7;
        }
        for (; k + 15 < e; k += 16) {
            uint4 iv = *(const uint4*)(adjL + k + slot * 4);
            uint w0 = h2_16[iv.x * 16 + p];
            uint w1 = h2_16[iv.y * 16 + p];
            uint w2 = h2_16[iv.z * 16 + p];
            uint w3 = h2_16[iv.w * 16 + p];
            float vx0 = hx - bf_lo(w0), vy0 = hy - bf_hi(w0);
            float vx1 = hx - bf_lo(w1), vy1 = hy - bf_hi(w1);
            float vx2 = hx - bf_lo(w2), vy2 = hy - bf_hi(w2);
            float vx3 = hx - bf_lo(w3), vy3 = hy - bf_hi(w3);
            ax0 += vx0 * vx0; ay0 += vy0 * vy0;
            ax1 += vx1 * vx1; ay1 += vy1 * vy1;
            ax2 += vx2 * vx2; ay2 += vy2 * vy2;
            ax3 += vx3 * vx3; ay3 += vy3 * vy3;
        }
        for (; k < e; k += 4) {
            int kk = k + slot;
            if (kk < e) {
                uint w = h2_16[adjL[kk] * 16 + p];
                float vx = hx - bf_lo(w), vy = hy - bf_hi(w);
                ax0 += vx * vx; ay0 += vy * vy;
            }
        }
        float accx = (ax0 + ax1) + (ax2 + ax3);
        float accy = (ay0 + ay1) + (ay2 + ay3);
        accx += __shfl_xor(accx, 16); accy += __shfl_xor(accy, 16);
        accx += __shfl_xor(accx, 32); accy += __shfl_xor(accy, 32);
        if (slot == 0) {
            float c = fmaxf((float)degL[nl], 1.f);
            float2 r;
            r.x = tanhf(accx / c);
            r.y = tanhf(accy / c);
            ((float2*)out)[(size_t)(nodeLo + nl) * 16 + p] = r;
        }
    }
}

// ---------------- fallback (atomic path, round-1, all f32) ----------------
__global__ void fb_count(const int* __restrict__ src, const int* __restrict__ dst,
                         int* __restrict__ degI, int* __restrict__ cntI, int E) {
    int j = blockIdx.x * blockDim.x + threadIdx.x;
    if (j < E) {
        atomicAdd(&degI[dst[j]], 1);
        atomicAdd(&cntI[src[j]], 1);
    }
}
__global__ void fb_dinv(const int* __restrict__ degI, float* __restrict__ dinv, int N) {
    int i = blockIdx.x * blockDim.x + threadIdx.x;
    if (i < N) dinv[i] = rsqrtf((float)(degI[i] + 1));
}
__global__ void fb_matmul(const float* __restrict__ X, const float* __restrict__ W,
                          const float* __restrict__ dinv, float* __restrict__ hs, int N) {
    __shared__ float Wl[D * D];
    __shared__ float Xl[8 * D];
    int tid = threadIdx.x;
    for (int k = tid; k < D * D; k += 256) Wl[k] = W[k];
    int row0 = blockIdx.x * 8;
    int g = row0 * D + tid;
    Xl[tid] = (g < N * D) ? X[g] : 0.f;
    __syncthreads();
    int r = tid >> 5;
    int d = tid & 31;
    int row = row0 + r;
    if (row < N) {
        float acc = 0.f;
        #pragma unroll
        for (int k = 0; k < D; ++k) acc += Xl[r * D + k] * Wl[k * D + d];
        hs[row * D + d] = acc * dinv[row];
    }
}
__global__ void fb_scatter_conv(const int* __restrict__ src, const int* __restrict__ dst,
                                const float* __restrict__ hs, float* __restrict__ S, int ED) {
    int idx = blockIdx.x * blockDim.x + threadIdx.x;
    if (idx < ED) {
        int j = idx >> 5, d = idx & 31;
        atomicAdd(&S[dst[j] * D + d], hs[src[j] * D + d]);
    }
}
__global__ void fb_h2(float* __restrict__ S, const float* __restrict__ hs,
                      const float* __restrict__ dinv, const float* __restrict__ b, int ND) {
    int idx = blockIdx.x * blockDim.x + threadIdx.x;
    if (idx < ND) {
        int i = idx >> 5, d = idx & 31;
        float v = dinv[i] * (S[idx] + hs[idx]) + b[d];
        S[idx] = fmaxf(v, 0.f);
    }
}
__global__ void fb_edge_pow(const int* __restrict__ src, const int* __restrict__ dst,
                            const float* __restrict__ h2, float* __restrict__ out, int ED) {
    int idx = blockIdx.x * blockDim.x + threadIdx.x;
    if (idx < ED) {
        int j = idx >> 5, d = idx & 31;
        float v = h2[src[j] * D + d] - h2[dst[j] * D + d];
        atomicAdd(&out[src[j] * D + d], v * v);
    }
}
__global__ void fb_finalize(float* __restrict__ out, const int* __restrict__ cntI, int ND) {
    int idx = blockIdx.x * blockDim.x + threadIdx.x;
    if (idx < ND) {
        int i = idx >> 5;
        float c = fmaxf((float)cntI[i], 1.f);
        out[idx] = tanhf(out[idx] / c);
    }
}

extern "C" void kernel_launch(void* const* d_in, const int* in_sizes, int n_in,
                              void* d_out, int out_size, void* d_ws, size_t ws_size,
                              hipStream_t stream) {
    const float* X  = (const float*)d_in[0];
    const int*   ei = (const int*)d_in[1];
    const float* W  = (const float*)d_in[2];
    const float* b  = (const float*)d_in[3];
    int N = in_sizes[0] / D;
    int E = in_sizes[1] / 2;
    const int* src = ei;
    const int* dst = ei + E;
    float* out = (float*)d_out;

    size_t ND = (size_t)N * D;
    size_t NH = (size_t)N * 16;                   // packed bf16 row = 16 dwords
    int nb = (N + 63) >> CSH;                     // 64-node buckets
    int cap = ((E + nb - 1) / nb + 768 + 15) & ~15;    // mean + ~17 sigma slack
    size_t capSz = (size_t)nb * cap;
    size_t ldsBytes = (size_t)cap * 4;            // fused kernels' dynamic LDS

    uint* coarseD = (uint*)d_ws;                  // capSz
    uint* coarseS = coarseD + capSz;              // capSz
    uint* hs16   = coarseS + capSz;               // NH
    uint* h2_16  = hs16 + NH;                     // NH
    int* gCurD  = (int*)(h2_16 + NH);             // NBMAX
    int* gCurS  = gCurD + NBMAX;                  // NBMAX
    size_t need = (2 * capSz + 2 * NH + 2 * NBMAX) * 4;

    if (ws_size >= need && nb <= NBMAX && N <= (1 << PSH) && capSz < (1u << 30)
        && ldsBytes <= 48 * 1024) {
        zero_kernel<<<2, 1024, 0, stream>>>(gCurD, 2 * NBMAX);   // gCurD+gCurS contiguous
        int cgrid = (E + 4095) / 4096;
        coarse_scatter<<<cgrid, 1024, 0, stream>>>(src, dst, gCurD, gCurS,
                                                   coarseD, coarseS, E, cap);
        matmul_deg_kernel<<<nb, 512, 0, stream>>>(X, W, coarseD, gCurD, hs16, N, cap);
        conv_fused<<<nb, 512, ldsBytes, stream>>>(coarseD, gCurD, hs16, b, h2_16, N, cap);
        pow_fused<<<nb, 512, ldsBytes, stream>>>(coarseS, gCurS, h2_16, out, N, cap);
    } else {
        float* fhs  = (float*)d_ws;
        float* S    = fhs + ND;
        float* fdv  = S + ND;
        int*   fdeg = (int*)(fdv + N);
        int*   fcnt = fdeg + N;
        hipMemsetAsync(S, 0, ND * sizeof(float), stream);
        hipMemsetAsync(fdeg, 0, (size_t)2 * N * sizeof(int), stream);
        hipMemsetAsync(d_out, 0, ND * sizeof(float), stream);
        int EDi = E * D, NDi = (int)ND;
        fb_count<<<(E + 255) / 256, 256, 0, stream>>>(src, dst, fdeg, fcnt, E);
        fb_dinv<<<(N + 255) / 256, 256, 0, stream>>>(fdeg, fdv, N);
        fb_matmul<<<(N + 7) / 8, 256, 0, stream>>>(X, W, fdv, fhs, N);
        fb_scatter_conv<<<(EDi + 255) / 256, 256, 0, stream>>>(src, dst, fhs, S, EDi);
        fb_h2<<<(NDi + 255) / 256, 256, 0, stream>>>(S, fhs, fdv, b, NDi);
        fb_edge_pow<<<(EDi + 255) / 256, 256, 0, stream>>>(src, dst, S, out, EDi);
        fb_finalize<<<(NDi + 255) / 256, 256, 0, stream>>>(out, fcnt, NDi);
    }
}

// Round 20
// 89.686 us; speedup vs baseline: 1.0536x; 1.0536x over previous
//
#include <hip/hip_runtime.h>

#define D 32
#define CSH 7                      // 128 nodes per coarse bucket
#define KMASK 127
#define PSH 23                     // payload bits (node id) -> N must be <= 2^23
#define PMASK ((1u << PSH) - 1u)
#define NBMAX 512

typedef unsigned int uint;

// f32 -> bf16 round-to-nearest-even, and pack/unpack helpers
__device__ inline uint bf16rne(float f) {
    uint u = __float_as_uint(f);
    return (u + 0x7FFFu + ((u >> 16) & 1u)) >> 16;
}
__device__ inline float bf_lo(uint w) { return __uint_as_float(w << 16); }
__device__ inline float bf_hi(uint w) { return __uint_as_float(w & 0xFFFF0000u); }
__device__ inline uint bf_pack(float x, float y) { return bf16rne(x) | (bf16rne(y) << 16); }

// ---- zero the bucket cursors ----
__global__ void zero_kernel(int* __restrict__ p, int n) {
    int i = threadIdx.x;
    if (i < n) p[i] = 0;
}

// ---- merged coarse scatter with LDS staging; wave-shfl scans (3 barriers) ----
__global__ void __launch_bounds__(1024)
coarse_scatter(const int* __restrict__ src, const int* __restrict__ dst,
               int* __restrict__ gCurD, int* __restrict__ gCurS,
               uint* __restrict__ coarseD, uint* __restrict__ coarseS,
               int E, int cap) {
    __shared__ uint stageD[4096], stageS[4096];          // 32 KB
    __shared__ int hD[NBMAX], hS[NBMAX];
    __shared__ int preD[NBMAX], preS[NBMAX];
    __shared__ int offD[NBMAX + 1], offS[NBMAX + 1];
    __shared__ int baseD[NBMAX], baseS[NBMAX];
    __shared__ int partial[16];
    int t = threadIdx.x;
    if (t < NBMAX) { hD[t] = 0; hS[t] = 0; }
    __syncthreads();
    int s[4], d[4], lpD[4], lpS[4];
    int j0 = blockIdx.x * 4096 + 4 * t;     // this thread's 4 consecutive edges
    int nv = 0;
    if (j0 + 3 < E) {
        int4 s4 = *(const int4*)(src + j0);
        int4 d4 = *(const int4*)(dst + j0);
        s[0] = s4.x; s[1] = s4.y; s[2] = s4.z; s[3] = s4.w;
        d[0] = d4.x; d[1] = d4.y; d[2] = d4.z; d[3] = d4.w;
        nv = 4;
    } else {
        for (int u = 0; u < 4; ++u) {
            int j = j0 + u;
            if (j < E) { s[nv] = src[j]; d[nv] = dst[j]; ++nv; }
        }
    }
    for (int u = 0; u < nv; ++u) {
        lpD[u] = atomicAdd(&hD[d[u] >> CSH], 1);
        lpS[u] = atomicAdd(&hS[s[u] >> CSH], 1);
    }
    __syncthreads();
    // wave-shfl dual scan: waves 0-7 scan hD, waves 8-15 scan hS
    {
        int w = t >> 6, l = t & 63;
        int idx = (w & 7) * 64 + l;
        int isS = w >> 3;
        int* h   = isS ? hS : hD;
        int* pre = isS ? preS : preD;
        int v = h[idx];
        int incl = v;
        #pragma unroll
        for (int off = 1; off < 64; off <<= 1) {
            int x = __shfl_up(incl, off, 64);
            if (l >= off) incl += x;
        }
        pre[idx] = incl;                         // inclusive within wave
        if (l == 63) partial[w] = incl;
    }
    __syncthreads();
    if (t < 16) {                                // lanes 0-7: D partials, 8-15: S
        int v = partial[t];
        int incl = v;
        #pragma unroll
        for (int off = 1; off < 8; off <<= 1) {
            int x = __shfl_up(incl, off, 8);
            if ((t & 7) >= off) incl += x;
        }
        partial[t] = incl - v;                   // exclusive wave base
    }
    __syncthreads();
    {
        int w = t >> 6, l = t & 63;
        int idx = (w & 7) * 64 + l;
        int isS = w >> 3;
        int* h    = isS ? hS : hD;
        int* pre  = isS ? preS : preD;
        int* off_ = isS ? offS : offD;
        int* base = isS ? baseS : baseD;
        int* gC   = isS ? gCurS : gCurD;
        int incl = pre[idx] + partial[w];
        off_[idx] = incl - h[idx];               // exclusive prefix
        if (h[idx]) base[idx] = atomicAdd(&gC[idx], h[idx]);
        if (idx == NBMAX - 1) off_[NBMAX] = incl;
    }
    __syncthreads();
    // scatter into LDS stage, ordered by bucket
    for (int u = 0; u < nv; ++u) {
        stageD[offD[d[u] >> CSH] + lpD[u]] = ((uint)(d[u] & KMASK) << PSH) | (uint)s[u];
        stageS[offS[s[u] >> CSH] + lpS[u]] = ((uint)(s[u] & KMASK) << PSH) | (uint)d[u];
    }
    __syncthreads();
    // coalesced copy-out: consecutive threads write consecutive run entries
    int totD = offD[NBMAX];
    for (int j = t; j < totD; j += 1024) {
        int lo = 0, hi = NBMAX;                  // largest b with offD[b] <= j
        while (hi - lo > 1) { int mid = (lo + hi) >> 1; if (offD[mid] <= j) lo = mid; else hi = mid; }
        int rel = baseD[lo] + (j - offD[lo]);
        if (rel < cap) coarseD[(size_t)lo * cap + rel] = stageD[j];
    }
    int totS = offS[NBMAX];
    for (int j = t; j < totS; j += 1024) {
        int lo = 0, hi = NBMAX;
        while (hi - lo > 1) { int mid = (lo + hi) >> 1; if (offS[mid] <= j) lo = mid; else hi = mid; }
        int rel = baseS[lo] + (j - offS[lo]);
        if (rel < cap) coarseS[(size_t)lo * cap + rel] = stageS[j];
    }
}

// ---- merged deg histogram + dense matmul: hs16[i] = bf16((X[i]@W) * rsqrt(deg+1)) ----
__global__ void __launch_bounds__(1024)
matmul_deg_kernel(const float* __restrict__ X, const float* __restrict__ W,
                  const uint* __restrict__ coarseD, const int* __restrict__ gCurD,
                  uint* __restrict__ hs16, int N, int cap) {
    __shared__ float Wl[D * D];        // 4 KB
    __shared__ float Xl[128 * D];      // 16 KB
    __shared__ int cnt[128];
    int b = blockIdx.x, t = threadIdx.x;   // 1024
    int nodeLo = b << CSH;
    if (t < 128) cnt[t] = 0;
    if (t < D * D) Wl[t] = W[t];
    // stage X rows for this bucket (4 elements per thread)
    for (int i = t; i < 128 * D; i += 1024) {
        int node = nodeLo + (i >> 5);
        Xl[i] = (node < N) ? X[(size_t)node * D + (i & 31)] : 0.f;
    }
    __syncthreads();
    // histogram of coarseD bucket -> per-node in-degree
    size_t lo = (size_t)b * cap;
    int n = min(gCurD[b], cap - 512);
    int n4 = n >> 2;
    const uint4* c4 = (const uint4*)(coarseD + lo);
    for (int kk = t; kk < n4; kk += 1024) {
        uint4 e4 = c4[kk];
        atomicAdd(&cnt[e4.x >> PSH], 1);
        atomicAdd(&cnt[e4.y >> PSH], 1);
        atomicAdd(&cnt[e4.z >> PSH], 1);
        atomicAdd(&cnt[e4.w >> PSH], 1);
    }
    for (int kk = 4 * n4 + t; kk < n; kk += 1024)
        atomicAdd(&cnt[coarseD[lo + kk] >> PSH], 1);
    __syncthreads();
    // 4 passes of 32 rows x 32 cols
    int c = t & 31;
    #pragma unroll
    for (int pass = 0; pass < 4; ++pass) {
        int r = pass * 32 + (t >> 5);
        int node = nodeLo + r;
        float acc = 0.f;
        #pragma unroll
        for (int k = 0; k < D; ++k) acc += Xl[r * D + k] * Wl[k * D + c];
        acc *= rsqrtf((float)(cnt[r] + 1));              // +1 self-loop
        float other = __shfl_xor(acc, 1);
        if (node < N && (c & 1) == 0)
            hs16[(size_t)node * 16 + (c >> 1)] = bf_pack(acc, other);
    }
}

// ---- fused D-direction sort + conv gather; wave-shfl scan (2 barriers in sort) ----
__global__ void __launch_bounds__(1024)
conv_fused(const uint* __restrict__ coarseD, const int* __restrict__ gCurD,
           const uint* __restrict__ hs16, const float* __restrict__ bias,
           uint* __restrict__ h2_16, int N, int cap) {
    extern __shared__ uint adjL[];               // cap entries (dynamic LDS)
    __shared__ int cnt[128];
    __shared__ int rs[128];
    __shared__ int degL[128];
    int b = blockIdx.x;
    int t = threadIdx.x;   // 1024
    int nodeLo = b << CSH;
    int nNodes = min(128, N - nodeLo);
    if (t < 128) cnt[t] = 0;
    __syncthreads();
    size_t lo = (size_t)b * cap;
    int n = min(gCurD[b], cap - 512);
    int n4 = n >> 2;
    const uint4* c4 = (const uint4*)(coarseD + lo);
    for (int kk = t; kk < n4; kk += 1024) {
        uint4 e4 = c4[kk];
        atomicAdd(&cnt[e4.x >> PSH], 1);
        atomicAdd(&cnt[e4.y >> PSH], 1);
        atomicAdd(&cnt[e4.z >> PSH], 1);
        atomicAdd(&cnt[e4.w >> PSH], 1);
    }
    for (int kk = 4 * n4 + t; kk < n; kk += 1024)
        atomicAdd(&cnt[coarseD[lo + kk] >> PSH], 1);
    __syncthreads();
    if (t < 64) {                                // wave-synchronous 128-entry scan
        int a = cnt[2 * t], b2 = cnt[2 * t + 1];
        int pa = (a + 3) & ~3, pb = (b2 + 3) & ~3;
        int local = pa + pb;
        int incl = local;
        #pragma unroll
        for (int off = 1; off < 64; off <<= 1) {
            int x = __shfl_up(incl, off, 64);
            if (t >= off) incl += x;
        }
        int excl = incl - local;
        rs[2 * t] = excl;      rs[2 * t + 1] = excl + pa;
        degL[2 * t] = a;       degL[2 * t + 1] = b2;
        cnt[2 * t] = excl;     cnt[2 * t + 1] = excl + pa;   // cursors
    }
    __syncthreads();
    for (int kk = t; kk < n; kk += 1024) {       // scatter (coarse is L2-hot)
        uint e = coarseD[lo + kk];
        int pos = atomicAdd(&cnt[e >> PSH], 1);
        if (pos < cap) adjL[pos] = e & PMASK;
    }
    __syncthreads();
    // gather phase: wave w handles nodes w, w+16, w+32, ...
    int wave = t >> 6, lane = t & 63;
    int p = lane & 15, slot = lane >> 4;
    for (int nl = wave; nl < nNodes; nl += 16) {
        int s = rs[nl];
        int e = s + degL[nl];
        float ax0 = 0.f, ay0 = 0.f, ax1 = 0.f, ay1 = 0.f;
        float ax2 = 0.f, ay2 = 0.f, ax3 = 0.f, ay3 = 0.f;
        int k = s;
        for (; k + 31 < e; k += 32) {            // 8 row-gathers in flight
            uint4 iv0 = *(const uint4*)(adjL + k + slot * 4);
            uint4 iv1 = *(const uint4*)(adjL + k + 16 + slot * 4);
            uint w0 = hs16[iv0.x * 16 + p];
            uint w1 = hs16[iv0.y * 16 + p];
            uint w2 = hs16[iv0.z * 16 + p];
            uint w3 = hs16[iv0.w * 16 + p];
            uint w4 = hs16[iv1.x * 16 + p];
            uint w5 = hs16[iv1.y * 16 + p];
            uint w6 = hs16[iv1.z * 16 + p];
            uint w7 = hs16[iv1.w * 16 + p];
            ax0 += bf_lo(w0); ay0 += bf_hi(w0);
            ax1 += bf_lo(w1); ay1 += bf_hi(w1);
            ax2 += bf_lo(w2); ay2 += bf_hi(w2);
            ax3 += bf_lo(w3); ay3 += bf_hi(w3);
            ax0 += bf_lo(w4); ay0 += bf_hi(w4);
            ax1 += bf_lo(w5); ay1 += bf_hi(w5);
            ax2 += bf_lo(w6); ay2 += bf_hi(w6);
            ax3 += bf_lo(w7); ay3 += bf_hi(w7);
        }
        for (; k + 15 < e; k += 16) {
            uint4 iv = *(const uint4*)(adjL + k + slot * 4);
            uint w0 = hs16[iv.x * 16 + p];
            uint w1 = hs16[iv.y * 16 + p];
            uint w2 = hs16[iv.z * 16 + p];
            uint w3 = hs16[iv.w * 16 + p];
            ax0 += bf_lo(w0); ay0 += bf_hi(w0);
            ax1 += bf_lo(w1); ay1 += bf_hi(w1);
            ax2 += bf_lo(w2); ay2 += bf_hi(w2);
            ax3 += bf_lo(w3); ay3 += bf_hi(w3);
        }
        for (; k < e; k += 4) {
            int kk = k + slot;
            if (kk < e) {
                uint w = hs16[adjL[kk] * 16 + p];
                ax0 += bf_lo(w); ay0 += bf_hi(w);
            }
        }
        float accx = (ax0 + ax1) + (ax2 + ax3);
        float accy = (ay0 + ay1) + (ay2 + ay3);
        accx += __shfl_xor(accx, 16); accy += __shfl_xor(accy, 16);
        accx += __shfl_xor(accx, 32); accy += __shfl_xor(accy, 32);
        if (slot == 0) {
            int node = nodeLo + nl;
            uint wself = hs16[(size_t)node * 16 + p];
            float di = rsqrtf((float)(degL[nl] + 1));
            float vx = di * (accx + bf_lo(wself)) + bias[2 * p];
            float vy = di * (accy + bf_hi(wself)) + bias[2 * p + 1];
            h2_16[(size_t)node * 16 + p] = bf_pack(fmaxf(vx, 0.f), fmaxf(vy, 0.f));
        }
    }
}

// ---- fused S-direction sort + pow gather; wave-shfl scan ----
__global__ void __launch_bounds__(1024)
pow_fused(const uint* __restrict__ coarseS, const int* __restrict__ gCurS,
          const uint* __restrict__ h2_16, float* __restrict__ out, int N, int cap) {
    extern __shared__ uint adjL[];               // cap entries (dynamic LDS)
    __shared__ int cnt[128];
    __shared__ int rs[128];
    __shared__ int degL[128];
    __shared__ uint self[128 * 16];              // 8 KB
    int b = blockIdx.x;
    int t = threadIdx.x;   // 1024
    int nodeLo = b << CSH;
    int nNodes = min(128, N - nodeLo);
    if (t < 128) cnt[t] = 0;
    for (int i = t; i < nNodes * 16; i += 1024)
        self[i] = h2_16[(size_t)(nodeLo + (i >> 4)) * 16 + (i & 15)];
    __syncthreads();
    size_t lo = (size_t)b * cap;
    int n = min(gCurS[b], cap - 512);
    int n4 = n >> 2;
    const uint4* c4 = (const uint4*)(coarseS + lo);
    for (int kk = t; kk < n4; kk += 1024) {
        uint4 e4 = c4[kk];
        atomicAdd(&cnt[e4.x >> PSH], 1);
        atomicAdd(&cnt[e4.y >> PSH], 1);
        atomicAdd(&cnt[e4.z >> PSH], 1);
        atomicAdd(&cnt[e4.w >> PSH], 1);
    }
    for (int kk = 4 * n4 + t; kk < n; kk += 1024)
        atomicAdd(&cnt[coarseS[lo + kk] >> PSH], 1);
    __syncthreads();
    if (t < 64) {                                // wave-synchronous 128-entry scan
        int a = cnt[2 * t], b2 = cnt[2 * t + 1];
        int pa = (a + 3) & ~3, pb = (b2 + 3) & ~3;
        int local = pa + pb;
        int incl = local;
        #pragma unroll
        for (int off = 1; off < 64; off <<= 1) {
            int x = __shfl_up(incl, off, 64);
            if (t >= off) incl += x;
        }
        int excl = incl - local;
        rs[2 * t] = excl;      rs[2 * t + 1] = excl + pa;
        degL[2 * t] = a;       degL[2 * t + 1] = b2;
        cnt[2 * t] = excl;     cnt[2 * t + 1] = excl + pa;   // cursors
    }
    __syncthreads();
    for (int kk = t; kk < n; kk += 1024) {       // scatter (coarse is L2-hot)
        uint e = coarseS[lo + kk];
        int pos = atomicAdd(&cnt[e >> PSH], 1);
        if (pos < cap) adjL[pos] = e & PMASK;
    }
    __syncthreads();
    // gather phase: wave w handles nodes w, w+16, w+32, ...
    int wave = t >> 6, lane = t & 63;
    int p = lane & 15, slot = lane >> 4;
    for (int nl = wave; nl < nNodes; nl += 16) {
        int s = rs[nl];
        int e = s + degL[nl];
        uint wh = self[nl * 16 + p];
        float hx = bf_lo(wh), hy = bf_hi(wh);
        float ax0 = 0.f, ay0 = 0.f, ax1 = 0.f, ay1 = 0.f;
        float ax2 = 0.f, ay2 = 0.f, ax3 = 0.f, ay3 = 0.f;
        int k = s;
        for (; k + 31 < e; k += 32) {            // 8 row-gathers in flight
            uint4 iv0 = *(const uint4*)(adjL + k + slot * 4);
            uint4 iv1 = *(const uint4*)(adjL + k + 16 + slot * 4);
            uint w0 = h2_16[iv0.x * 16 + p];
            uint w1 = h2_16[iv0.y * 16 + p];
            uint w2 = h2_16[iv0.z * 16 + p];
            uint w3 = h2_16[iv0.w * 16 + p];
            uint w4 = h2_16[iv1.x * 16 + p];
            uint w5 = h2_16[iv1.y * 16 + p];
            uint w6 = h2_16[iv1.z * 16 + p];
            uint w7 = h2_16[iv1.w * 16 + p];
            float vx0 = hx - bf_lo(w0), vy0 = hy - bf_hi(w0);
            float vx1 = hx - bf_lo(w1), vy1 = hy - bf_hi(w1);
            float vx2 = hx - bf_lo(w2), vy2 = hy - bf_hi(w2);
            float vx3 = hx - bf_lo(w3), vy3 = hy - bf_hi(w3);
            ax0 += vx0 * vx0; ay0 += vy0 * vy0;
            ax1 += vx1 * vx1; ay1 += vy1 * vy1;
            ax2 += vx2 * vx2; ay2 += vy2 * vy2;
            ax3 += vx3 * vx3; ay3 += vy3 * vy3;
            float vx4 = hx - bf_lo(w4), vy4 = hy - bf_hi(w4);
            float vx5 = hx - bf_lo(w5), vy5 = hy - bf_hi(w5);
            float vx6 = hx - bf_lo(w6), vy6 = hy - bf_hi(w6);
            float vx7 = hx - bf_lo(w7), vy7 = hy - bf_hi(w7);
            ax0 += vx4 * vx4; ay0 += vy4 * vy4;
            ax1 += vx5 * vx5; ay1 += vy5 * vy5;
            ax2 += vx6 * vx6; ay2 += vy6 * vy6;
            ax3 += vx7 * vx7; ay3 += vy7 * vy7;
        }
        for (; k + 15 < e; k += 16) {
            uint4 iv = *(const uint4*)(adjL + k + slot * 4);
            uint w0 = h2_16[iv.x * 16 + p];
            uint w1 = h2_16[iv.y * 16 + p];
            uint w2 = h2_16[iv.z * 16 + p];
            uint w3 = h2_16[iv.w * 16 + p];
            float vx0 = hx - bf_lo(w0), vy0 = hy - bf_hi(w0);
            float vx1 = hx - bf_lo(w1), vy1 = hy - bf_hi(w1);
            float vx2 = hx - bf_lo(w2), vy2 = hy - bf_hi(w2);
            float vx3 = hx - bf_lo(w3), vy3 = hy - bf_hi(w3);
            ax0 += vx0 * vx0; ay0 += vy0 * vy0;
            ax1 += vx1 * vx1; ay1 += vy1 * vy1;
            ax2 += vx2 * vx2; ay2 += vy2 * vy2;
            ax3 += vx3 * vx3; ay3 += vy3 * vy3;
        }
        for (; k < e; k += 4) {
            int kk = k + slot;
            if (kk < e) {
                uint w = h2_16[adjL[kk] * 16 + p];
                float vx = hx - bf_lo(w), vy = hy - bf_hi(w);
                ax0 += vx * vx; ay0 += vy * vy;
            }
        }
        float accx = (ax0 + ax1) + (ax2 + ax3);
        float accy = (ay0 + ay1) + (ay2 + ay3);
        accx += __shfl_xor(accx, 16); accy += __shfl_xor(accy, 16);
        accx += __shfl_xor(accx, 32); accy += __shfl_xor(accy, 32);
        if (slot == 0) {
            float c = fmaxf((float)degL[nl], 1.f);
            float2 r;
            r.x = tanhf(accx / c);
            r.y = tanhf(accy / c);
            ((float2*)out)[(size_t)(nodeLo + nl) * 16 + p] = r;
        }
    }
}

// ---------------- fallback (atomic path, round-1, all f32) ----------------
__global__ void fb_count(const int* __restrict__ src, const int* __restrict__ dst,
                         int* __restrict__ degI, int* __restrict__ cntI, int E) {
    int j = blockIdx.x * blockDim.x + threadIdx.x;
    if (j < E) {
        atomicAdd(&degI[dst[j]], 1);
        atomicAdd(&cntI[src[j]], 1);
    }
}
__global__ void fb_dinv(const int* __restrict__ degI, float* __restrict__ dinv, int N) {
    int i = blockIdx.x * blockDim.x + threadIdx.x;
    if (i < N) dinv[i] = rsqrtf((float)(degI[i] + 1));
}
__global__ void fb_matmul(const float* __restrict__ X, const float* __restrict__ W,
                          const float* __restrict__ dinv, float* __restrict__ hs, int N) {
    __shared__ float Wl[D * D];
    __shared__ float Xl[8 * D];
    int tid = threadIdx.x;
    for (int k = tid; k < D * D; k += 256) Wl[k] = W[k];
    int row0 = blockIdx.x * 8;
    int g = row0 * D + tid;
    Xl[tid] = (g < N * D) ? X[g] : 0.f;
    __syncthreads();
    int r = tid >> 5;
    int d = tid & 31;
    int row = row0 + r;
    if (row < N) {
        float acc = 0.f;
        #pragma unroll
        for (int k = 0; k < D; ++k) acc += Xl[r * D + k] * Wl[k * D + d];
        hs[row * D + d] = acc * dinv[row];
    }
}
__global__ void fb_scatter_conv(const int* __restrict__ src, const int* __restrict__ dst,
                                const float* __restrict__ hs, float* __restrict__ S, int ED) {
    int idx = blockIdx.x * blockDim.x + threadIdx.x;
    if (idx < ED) {
        int j = idx >> 5, d = idx & 31;
        atomicAdd(&S[dst[j] * D + d], hs[src[j] * D + d]);
    }
}
__global__ void fb_h2(float* __restrict__ S, const float* __restrict__ hs,
                      const float* __restrict__ dinv, const float* __restrict__ b, int ND) {
    int idx = blockIdx.x * blockDim.x + threadIdx.x;
    if (idx < ND) {
        int i = idx >> 5, d = idx & 31;
        float v = dinv[i] * (S[idx] + hs[idx]) + b[d];
        S[idx] = fmaxf(v, 0.f);
    }
}
__global__ void fb_edge_pow(const int* __restrict__ src, const int* __restrict__ dst,
                            const float* __restrict__ h2, float* __restrict__ out, int ED) {
    int idx = blockIdx.x * blockDim.x + threadIdx.x;
    if (idx < ED) {
        int j = idx >> 5, d = idx & 31;
        float v = h2[src[j] * D + d] - h2[dst[j] * D + d];
        atomicAdd(&out[src[j] * D + d], v * v);
    }
}
__global__ void fb_finalize(float* __restrict__ out, const int* __restrict__ cntI, int ND) {
    int idx = blockIdx.x * blockDim.x + threadIdx.x;
    if (idx < ND) {
        int i = idx >> 5;
        float c = fmaxf((float)cntI[i], 1.f);
        out[idx] = tanhf(out[idx] / c);
    }
}

extern "C" void kernel_launch(void* const* d_in, const int* in_sizes, int n_in,
                              void* d_out, int out_size, void* d_ws, size_t ws_size,
                              hipStream_t stream) {
    const float* X  = (const float*)d_in[0];
    const int*   ei = (const int*)d_in[1];
    const float* W  = (const float*)d_in[2];
    const float* b  = (const float*)d_in[3];
    int N = in_sizes[0] / D;
    int E = in_sizes[1] / 2;
    const int* src = ei;
    const int* dst = ei + E;
    float* out = (float*)d_out;

    size_t ND = (size_t)N * D;
    size_t NH = (size_t)N * 16;                   // packed bf16 row = 16 dwords
    int nb = (N + 127) >> CSH;                    // 128-node buckets
    int cap = ((E + nb - 1) / nb + 1024 + 15) & ~15;   // mean + ~16 sigma slack
    size_t capSz = (size_t)nb * cap;
    size_t ldsBytes = (size_t)cap * 4;            // fused kernels' dynamic LDS

    uint* coarseD = (uint*)d_ws;                  // capSz
    uint* coarseS = coarseD + capSz;              // capSz
    uint* hs16   = coarseS + capSz;               // NH
    uint* h2_16  = hs16 + NH;                     // NH
    int* gCurD  = (int*)(h2_16 + NH);             // NBMAX
    int* gCurS  = gCurD + NBMAX;                  // NBMAX
    size_t need = (2 * capSz + 2 * NH + 2 * NBMAX) * 4;

    if (ws_size >= need && nb <= NBMAX && N <= (1 << PSH) && capSz < (1u << 30)
        && ldsBytes <= 96 * 1024) {
        zero_kernel<<<1, 1024, 0, stream>>>(gCurD, 2 * NBMAX);   // gCurD+gCurS contiguous
        int cgrid = (E + 4095) / 4096;
        coarse_scatter<<<cgrid, 1024, 0, stream>>>(src, dst, gCurD, gCurS,
                                                   coarseD, coarseS, E, cap);
        matmul_deg_kernel<<<nb, 1024, 0, stream>>>(X, W, coarseD, gCurD, hs16, N, cap);
        conv_fused<<<nb, 1024, ldsBytes, stream>>>(coarseD, gCurD, hs16, b, h2_16, N, cap);
        pow_fused<<<nb, 1024, ldsBytes, stream>>>(coarseS, gCurS, h2_16, out, N, cap);
    } else {
        float* fhs  = (float*)d_ws;
        float* S    = fhs + ND;
        float* fdv  = S + ND;
        int*   fdeg = (int*)(fdv + N);
        int*   fcnt = fdeg + N;
        hipMemsetAsync(S, 0, ND * sizeof(float), stream);
        hipMemsetAsync(fdeg, 0, (size_t)2 * N * sizeof(int), stream);
        hipMemsetAsync(d_out, 0, ND * sizeof(float), stream);
        int EDi = E * D, NDi = (int)ND;
        fb_count<<<(E + 255) / 256, 256, 0, stream>>>(src, dst, fdeg, fcnt, E);
        fb_dinv<<<(N + 255) / 256, 256, 0, stream>>>(fdeg, fdv, N);
        fb_matmul<<<(N + 7) / 8, 256, 0, stream>>>(X, W, fdv, fhs, N);
        fb_scatter_conv<<<(EDi + 255) / 256, 256, 0, stream>>>(src, dst, fhs, S, EDi);
        fb_h2<<<(NDi + 255) / 256, 256, 0, stream>>>(S, fhs, fdv, b, NDi);
        fb_edge_pow<<<(EDi + 255) / 256, 256, 0, stream>>>(src, dst, S, out, EDi);
        fb_finalize<<<(NDi + 255) / 256, 256, 0, stream>>>(out, fcnt, NDi);
    }
}